// Round 3
// baseline (421.982 us; speedup 1.0000x reference)
//
#include <hip/hip_runtime.h>

#define EPSF 1e-8f
#define HALF_PI 1.5707963267948966f
#define TWO_PI  6.283185307179586f

typedef float f32x4 __attribute__((ext_vector_type(4)));  // native vec for NT builtins

// image layout: (B=16, C=3, H*W = 1<<20), fp32.
// Each thread processes 8 consecutive pixels of one (b) image -> 2x f32x4
// nontemporal loads from each of the R, G, B planes and 2x f32x4
// nontemporal stores to each of the X, Y, Z planes. All streams are
// read-once / write-once, so NT (L2-bypass) is strictly beneficial.
__global__ __launch_bounds__(256) void rgb2hvi_kernel(
    const float* __restrict__ img,
    const float* __restrict__ kptr,
    float* __restrict__ out,
    int n8)  // total pixels / 8
{
    int tid = blockIdx.x * blockDim.x + threadIdx.x;
    if (tid >= n8) return;

    const float k = kptr[0];          // uniform -> scalar load

    const int HW = 1 << 20;           // 1024*1024
    long long i = (long long)tid << 3;            // flat pixel index
    int bidx = (int)(i >> 20);                    // batch
    int p = (int)(i & (HW - 1));                  // pixel within image
    long long base = (long long)bidx * (3LL * HW) + p;

    const f32x4* rp = (const f32x4*)(img + base);
    const f32x4* gp = (const f32x4*)(img + base + HW);
    const f32x4* bp = (const f32x4*)(img + base + 2 * HW);

    f32x4 r4[2], g4[2], b4[2];
    r4[0] = __builtin_nontemporal_load(rp);
    r4[1] = __builtin_nontemporal_load(rp + 1);
    g4[0] = __builtin_nontemporal_load(gp);
    g4[1] = __builtin_nontemporal_load(gp + 1);
    b4[0] = __builtin_nontemporal_load(bp);
    b4[1] = __builtin_nontemporal_load(bp + 1);

    float X[8], Y[8], Z[8];

#pragma unroll
    for (int j = 0; j < 8; ++j) {
        float r = r4[j >> 2][j & 3];
        float g = g4[j >> 2][j & 3];
        float b = b4[j >> 2][j & 3];

        float v  = fmaxf(r, fmaxf(g, b));
        float mn = fminf(r, fminf(g, b));
        float denom = v - mn + EPSF;
        float invd = __builtin_amdgcn_rcpf(denom);   // ~2^-22 rel err

        // hue candidates
        float hr = (g - b) * invd;                   // in (-1, 1)
        hr = (hr < 0.0f) ? hr + 6.0f : hr;           // floor-mod 6 on (-1,1)
        float hg = 2.0f + (b - r) * invd;
        float hb = 4.0f + (r - g) * invd;

        // jnp.where chain, last-wins priority: min > r > g > b
        float hue = (b  == v) ? hb   : 0.0f;
        hue       = (g  == v) ? hg   : hue;
        hue       = (r  == v) ? hr   : hue;
        hue       = (mn == v) ? 0.0f : hue;
        hue *= (1.0f / 6.0f);

        float sat = (v == 0.0f) ? 0.0f
                                : (v - mn) * __builtin_amdgcn_rcpf(v + EPSF);

        // color_sensitive = (sin(v*pi/2) + eps)^k ; base > 0 always
        float cs = __powf(__sinf(v * HALF_PI) + EPSF, k);

        float ang = TWO_PI * hue;
        float cx = __cosf(ang);
        float cy = __sinf(ang);

        float s = cs * sat;
        X[j] = s * cx;
        Y[j] = s * cy;
        Z[j] = v;
    }

    f32x4* xp = (f32x4*)(out + base);
    f32x4* yp = (f32x4*)(out + base + HW);
    f32x4* zp = (f32x4*)(out + base + 2 * HW);

#pragma unroll
    for (int h = 0; h < 2; ++h) {
        f32x4 xv = { X[4*h+0], X[4*h+1], X[4*h+2], X[4*h+3] };
        f32x4 yv = { Y[4*h+0], Y[4*h+1], Y[4*h+2], Y[4*h+3] };
        f32x4 zv = { Z[4*h+0], Z[4*h+1], Z[4*h+2], Z[4*h+3] };
        __builtin_nontemporal_store(xv, xp + h);
        __builtin_nontemporal_store(yv, yp + h);
        __builtin_nontemporal_store(zv, zp + h);
    }
}

extern "C" void kernel_launch(void* const* d_in, const int* in_sizes, int n_in,
                              void* d_out, int out_size, void* d_ws, size_t ws_size,
                              hipStream_t stream) {
    const float* img  = (const float*)d_in[0];
    const float* kptr = (const float*)d_in[1];
    float* out = (float*)d_out;

    int total = in_sizes[0];          // 16*3*1024*1024
    int pixels = total / 3;           // 16*1024*1024
    int n8 = pixels / 8;              // 2097152

    int block = 256;
    int grid = (n8 + block - 1) / block;  // 8192
    rgb2hvi_kernel<<<grid, block, 0, stream>>>(img, kptr, out, n8);
}